// Round 9
// baseline (27.521 us; speedup 1.0000x reference)
//
#include <hip/hip_runtime.h>

// PBC nonlinear compensation, D-factorized, rolled/table-driven conv:
//   O[b,k,i] = E[b,k,i] + sum_m sm(k;m) * E[b,k-m,i]        (Re part stored)
//   sm(k;m)  = sum_n C[m,n] * D_m[k-n]
//   D_m[x]   = sum_j E_j[x] * conj(E_j[x-m]),  D_{-m}[x] = conj(D_m[x+m])
//
// 512 threads = 4 m-groups x 128 threads x 2 outputs. Rolled loops with a
// per-group (m, lim, tp, tn) table -> ~4 KB of code (vs ~100 KB unrolled;
// rounds 4-8 were invariant at 25.7 us across huge-code variants, consistent
// with cold-launch pricing via the fresh-launch tripwire). Per tap: two
// ds_read2_b64-fusable D pair-reads serve both outputs and both signs; C is
// read from global (uniform address -> scalar/L1 path, off the LDS pipe).

#define S_LEN 16384
#define SOUT  16284          // S - 2*L
#define BLK   512
#define NOUT  256            // outputs per block
#define NE    356            // staged E samples: [k0, k0+355]
#define ND    307            // D tile: x in [k0+25, k0+331]
#define ND_AL 308            // row stride (keeps rows 16B-aligned)

// Per-group m-lists: {m, lim, tp, tn}; tp = t_start(+m), tn = t_start(-m).
// Iteration balance (j-iters): g0=57, g1=59, g2=51(m0)+31, g3=52.
__device__ const int4 MLIST[25] = {
    // g0
    { 1,25,250,148}, {13, 1,410, 36}, {14, 1,413, 33},
    // g1
    { 2,12,301,123}, { 3, 8,326,106}, { 5, 5,356, 82}, {15, 1,416, 30},
    {16, 1,419, 27},
    // g2 (plus m=0 handled inline)
    { 4, 6,343, 93}, { 6, 4,367, 73}, {17, 1,422, 24}, {18, 1,425, 21},
    {19, 1,428, 18},
    // g3
    { 7, 3,376, 66}, { 8, 3,383, 59}, { 9, 2,390, 54}, {10, 2,395, 49},
    {11, 2,400, 44}, {12, 2,405, 39}, {20, 1,431, 15}, {21, 1,434, 12},
    {22, 1,437,  9}, {23, 1,440,  6}, {24, 1,443,  3}, {25, 1,446,  0}
};
__device__ const int GOFF[5] = {0, 3, 8, 13, 25};

__global__ __launch_bounds__(BLK, 4) void pbc_kernel(
    const float* __restrict__ Er, const float* __restrict__ Ei,
    const float* __restrict__ Cr, const float* __restrict__ Ci,
    float* __restrict__ out)
{
    __shared__ __align__(16) float4 sE[NE];            //  5.7 KB
    __shared__ __align__(16) float2 sD[25 * ND_AL];    // 61.6 KB (m = 1..25)
    __shared__ __align__(16) float  sD0[ND_AL];        //  1.2 KB (m = 0, real)
    __shared__ __align__(16) float4 sAcc[4][128];      //  8.0 KB partials

    const int b   = blockIdx.y;
    const int k0  = blockIdx.x * NOUT;
    const int tid = threadIdx.x;

    // ---- stage E tile: sE[kl] = E[k0 + kl] ----
    const float* erb = Er + (size_t)b * (S_LEN * 2);
    const float* eib = Ei + (size_t)b * (S_LEN * 2);
    for (int kl = tid; kl < NE; kl += BLK) {
        int kg = k0 + kl;
        float2 re = make_float2(0.f, 0.f), im = make_float2(0.f, 0.f);
        if (kg < S_LEN) {
            re = *reinterpret_cast<const float2*>(erb + 2 * kg);
            im = *reinterpret_cast<const float2*>(eib + 2 * kg);
        }
        sE[kl] = make_float4(re.x, im.x, re.y, im.y);
    }
    __syncthreads();

    // ---- all D tiles in one phase ----
    for (int xl = tid; xl < ND; xl += BLK) {
        float4 a = sE[xl + 25];
        sD0[xl] = a.x*a.x + a.y*a.y + a.z*a.z + a.w*a.w;
    }
    for (int idx = tid; idx < 25 * ND; idx += BLK) {
        int m1 = idx / ND;                 // 0..24 -> m = m1+1
        int xl = idx - m1 * ND;
        float4 a  = sE[xl + 25];
        float4 bb = sE[xl + 24 - m1];      // sE[xl + 25 - m]
        float gr = a.x*bb.x + a.y*bb.y + a.z*bb.z + a.w*bb.w;
        float gi = a.y*bb.x - a.x*bb.y + a.w*bb.z - a.z*bb.w;
        sD[m1 * ND_AL + xl] = make_float2(gr, gi);
    }
    __syncthreads();

    // ---- conv: 4 groups x 128 threads x 2 outputs (o0 = 2t, o0+1) ----
    const int g  = tid >> 7;            // wave-uniform (2 waves per group)
    const int t  = tid & 127;
    const int o0 = 2 * t;

    float4 acc = make_float4(0.f, 0.f, 0.f, 0.f);

    // m = 0 (real D), group 2 only
    if (g == 2) {
        float s0r=0.f, s0i=0.f, s1r=0.f, s1i=0.f;
        const int ib = o0 + 50;
        #pragma unroll 2
        for (int j = 0; j < 51; ++j) {
            float dA = sD0[ib - j];
            float dB = sD0[ib - j + 1];
            float cx = Cr[199 + j], cy = Ci[199 + j];
            s0r += cx * dA;  s0i += cy * dA;
            s1r += cx * dB;  s1i += cy * dB;
        }
        float4 e0 = sE[o0 + 50], e1 = sE[o0 + 51];
        acc.x += s0r*e0.x - s0i*e0.y;
        acc.y += s0r*e0.z - s0i*e0.w;
        acc.z += s1r*e1.x - s1i*e1.y;
        acc.w += s1r*e1.z - s1i*e1.w;
    }

    // m >= 1: both signs from one D_m tile
    const int e0i = GOFF[g], e1i = GOFF[g + 1];
    for (int e = e0i; e < e1i; ++e) {
        const int4 mm = MLIST[e];
        const int m = mm.x, lim = mm.y, tp = mm.z, tn = mm.w;
        const float2* __restrict__ Dm = sD + (m - 1) * ND_AL;
        const int ibase = o0 + 25 + lim;     // +m index at j=0 for out0

        float s0pr=0.f, s0pi=0.f, s1pr=0.f, s1pi=0.f;
        float s0nr=0.f, s0ni=0.f, s1nr=0.f, s1ni=0.f;
        #pragma unroll 2
        for (int j = 0; j < 2 * lim + 1; ++j) {
            const int i = ibase - j;
            float2 dA = Dm[i];          // +m, out0
            float2 dB = Dm[i + 1];      // +m, out1   (fuses with dA: read2)
            float2 dC = Dm[i + m];      // -m, out0 (conj)
            float2 dD = Dm[i + m + 1];  // -m, out1   (fuses with dC: read2)
            float cpx = Cr[tp + j], cpy = Ci[tp + j];
            float cnx = Cr[tn + j], cny = Ci[tn + j];
            s0pr += cpx*dA.x - cpy*dA.y;  s0pi += cpx*dA.y + cpy*dA.x;
            s1pr += cpx*dB.x - cpy*dB.y;  s1pi += cpx*dB.y + cpy*dB.x;
            s0nr += cnx*dC.x + cny*dC.y;  s0ni += cny*dC.x - cnx*dC.y;
            s1nr += cnx*dD.x + cny*dD.y;  s1ni += cny*dD.x - cnx*dD.y;
        }
        float4 ep0 = sE[o0 + 50 - m], ep1 = sE[o0 + 51 - m];
        float4 en0 = sE[o0 + 50 + m], en1 = sE[o0 + 51 + m];
        acc.x += s0pr*ep0.x - s0pi*ep0.y + s0nr*en0.x - s0ni*en0.y;
        acc.y += s0pr*ep0.z - s0pi*ep0.w + s0nr*en0.z - s0ni*en0.w;
        acc.z += s1pr*ep1.x - s1pi*ep1.y + s1nr*en1.x - s1ni*en1.y;
        acc.w += s1pr*ep1.z - s1pi*ep1.w + s1nr*en1.z - s1ni*en1.w;
    }

    sAcc[g][t] = acc;
    __syncthreads();

    // ---- combine: threads 0..127 sum the 4 partials and store ----
    if (tid < 128) {
        const int oo = 2 * tid;
        const int ko = k0 + oo;
        if (ko < SOUT) {
            float4 p0 = sAcc[0][tid], p1 = sAcc[1][tid];
            float4 p2 = sAcc[2][tid], p3 = sAcc[3][tid];
            float4 e0 = sE[oo + 50], e1 = sE[oo + 51];
            float4 o;
            o.x = e0.x + p0.x + p1.x + p2.x + p3.x;
            o.y = e0.z + p0.y + p1.y + p2.y + p3.y;
            o.z = e1.x + p0.z + p1.z + p2.z + p3.z;
            o.w = e1.z + p0.w + p1.w + p2.w + p3.w;
            *reinterpret_cast<float4*>(out + ((size_t)b * SOUT + ko) * 2) = o;
        }
    }
}

extern "C" void kernel_launch(void* const* d_in, const int* in_sizes, int n_in,
                              void* d_out, int out_size, void* d_ws, size_t ws_size,
                              hipStream_t stream) {
    const float* Er = (const float*)d_in[0];
    const float* Ei = (const float*)d_in[1];
    const float* Cr = (const float*)d_in[2];   // [4, 449], row 0 used
    const float* Ci = (const float*)d_in[3];
    float* out = (float*)d_out;                // [8, 16284, 2] float32 (Re)

    dim3 grid((SOUT + NOUT - 1) / NOUT, 8);
    pbc_kernel<<<grid, BLK, 0, stream>>>(Er, Ei, Cr, Ci, out);
}